// Round 6
// baseline (309.619 us; speedup 1.0000x reference)
//
#include <hip/hip_runtime.h>
#include <hip/hip_fp16.h>

// GNN fused pipeline on MI355X (gfx950).
//   CSR by dst via two-level counting sort (binA coarse, binB per-bucket)
//   norm_bn: z = BN(l2normalize(x)) -> Ah cols 128..255 (fp16)
//            zp = dinv*z            -> dense fp16 gather array
//   aggregate: y[i] = dinv_i*(sum_j zp[j] + zp[i]) -> Ah cols 0..127
//   out = leaky( Ah @ WhT^T + bias2 )  via fp16 MFMA 16x16x32, fp32 accum

#define NN 100000
#define DD 128
#define EE 1600000
#define BN_EPS 1e-5f
#define SLOPE 0.01f

#define NBKT 98          // ceil(NN / 1024)
#define BWID 1024        // nodes per bucket (dst >> 10)
#define CAPP 20480       // slack capacity per bucket (mean 16327, sd ~128)
#define EPB  4096        // edges per binA block -> 391 blocks

struct __align__(8) H4 { __half2 a, b; };   // 4 halves = 8 bytes

typedef _Float16 f16x8 __attribute__((ext_vector_type(8)));
typedef float    f32x4 __attribute__((ext_vector_type(4)));

// blocks 0..127: WhT[n][k] = fp16 of [W;rs_W][k][n]; block 128: bias2 + gcur init
__global__ void k_prep(const float* __restrict__ W, const float* __restrict__ rsW,
                       const float* __restrict__ b, const float* __restrict__ rb,
                       __half* __restrict__ WhT, float* __restrict__ bias2,
                       int* __restrict__ gcur) {
  int blk = blockIdx.x, t = threadIdx.x;
  if (blk == 128) {
    if (t < DD) bias2[t] = b[t] + rb[t];
    if (t < NBKT) gcur[t] = t * CAPP;
    return;
  }
  float v = (t < 128) ? W[t * 128 + blk] : rsW[(t - 128) * 128 + blk];
  WhT[blk * 256 + t] = __float2half(v);
}

// Phase A: coarse binning. Per-wave (4-way) LDS histograms; pair+bucket cached
// in LDS so pass 2 never re-reads global. One global atomic per (block,bucket).
// pairs[] entry: (local_dst << 17) | src
__global__ __launch_bounds__(256) void k_binA(const int* __restrict__ src,
                                              const int* __restrict__ dst,
                                              int* __restrict__ gcur,
                                              int* __restrict__ pairs) {
  __shared__ int hist[4][NBKT];
  __shared__ int cur[4][NBKT];
  __shared__ int pbuf[EPB];
  __shared__ unsigned char bbuf[EPB];
  int t = threadIdx.x;
  int w4 = t >> 6;
  for (int i = t; i < 4 * NBKT; i += 256) ((int*)hist)[i] = 0;
  __syncthreads();
  int e0 = blockIdx.x * EPB;
  #pragma unroll 4
  for (int i = 0; i < EPB / 256; ++i) {
    int idx = i * 256 + t;
    int e = e0 + idx;
    if (e < EE) {
      int d = dst[e], s = src[e];
      int bk = d >> 10;
      atomicAdd(&hist[w4][bk], 1);
      pbuf[idx] = ((d & 1023) << 17) | s;
      bbuf[idx] = (unsigned char)bk;
    }
  }
  __syncthreads();
  if (t < NBKT) {
    int h0 = hist[0][t], h1 = hist[1][t], h2 = hist[2][t], h3 = hist[3][t];
    int b0 = atomicAdd(&gcur[t], h0 + h1 + h2 + h3);
    cur[0][t] = b0;
    cur[1][t] = b0 + h0;
    cur[2][t] = b0 + h0 + h1;
    cur[3][t] = b0 + h0 + h1 + h2;
  }
  __syncthreads();
  #pragma unroll 4
  for (int i = 0; i < EPB / 256; ++i) {
    int idx = i * 256 + t;
    int e = e0 + idx;
    if (e < EE) {
      int bk = bbuf[idx];
      int r = atomicAdd(&cur[w4][bk], 1);
      pairs[r] = pbuf[idx];
    }
  }
}

// Phase B: one block per bucket; LDS histogram + scan -> dinv, startdeg; csr
// scatter within the bucket's exclusive region.
__global__ __launch_bounds__(1024) void k_binB(const int* __restrict__ gcur,
                                               const int* __restrict__ pairs,
                                               int* __restrict__ csr,
                                               int2* __restrict__ startdeg,
                                               float* __restrict__ dinv) {
  __shared__ int hist[BWID];
  __shared__ int excl[BWID];
  __shared__ int wsum[16];
  int b = blockIdx.x, t = threadIdx.x;
  hist[t] = 0;
  __syncthreads();
  int pbase = b * CAPP;
  int cnt = gcur[b] - pbase;
  for (int i = t; i < cnt; i += BWID)
    atomicAdd(&hist[pairs[pbase + i] >> 17], 1);
  __syncthreads();
  int v = hist[t];
  int lane = t & 63, w = t >> 6;
  int incl = v;
  #pragma unroll
  for (int off = 1; off < 64; off <<= 1) {
    int n = __shfl_up(incl, off, 64);
    if (lane >= off) incl += n;
  }
  if (lane == 63) wsum[w] = incl;
  __syncthreads();
  if (t < 16) {
    int orig = wsum[t];
    int s = orig;
    #pragma unroll
    for (int off = 1; off < 16; off <<= 1) {
      int n = __shfl_up(s, off, 64);
      if (t >= off) s += n;
    }
    wsum[t] = s - orig;
  }
  __syncthreads();
  int myexcl = (incl - v) + wsum[w];
  excl[t] = myexcl;
  int node = b * BWID + t;
  if (node < NN) {
    dinv[node] = rsqrtf((float)(v + 1));               // +1 self-loop
    startdeg[node] = make_int2(pbase + myexcl, v);
  }
  __syncthreads();
  for (int i = t; i < cnt; i += BWID) {
    int p = pairs[pbase + i];
    int pos = atomicAdd(&excl[p >> 17], 1);
    csr[pbase + pos] = p & 0x1FFFF;
  }
}

// fused row L2-normalize + BatchNorm(eval); one 64-lane wave per row.
// Writes fp16 z into Ah cols 128..255 and zp = dinv*z (dense fp16).
__global__ void k_norm_bn(const float* __restrict__ x,
                          const float* __restrict__ gamma,
                          const float* __restrict__ beta,
                          const float* __restrict__ mean,
                          const float* __restrict__ var,
                          const float* __restrict__ dinv,
                          __half* __restrict__ Ah, __half* __restrict__ zp) {
  int row = blockIdx.x * 4 + (threadIdx.x >> 6);
  int lane = threadIdx.x & 63;
  if (row >= NN) return;
  float2 v = ((const float2*)(x + (size_t)row * DD))[lane];
  float ss = v.x * v.x + v.y * v.y;
  #pragma unroll
  for (int off = 32; off > 0; off >>= 1) ss += __shfl_xor(ss, off);
  float s = 1.0f / fmaxf(sqrtf(ss), 1e-12f);
  float di = dinv[row];
  int c = lane * 2;
  float g0 = gamma[c]     * rsqrtf(var[c]     + BN_EPS);
  float g1 = gamma[c + 1] * rsqrtf(var[c + 1] + BN_EPS);
  float ox = (v.x * s - mean[c])     * g0 + beta[c];
  float oy = (v.y * s - mean[c + 1]) * g1 + beta[c + 1];
  ((__half2*)(Ah + (size_t)row * 256 + 128))[lane] = __floats2half2_rn(ox, oy);
  ((__half2*)(zp + (size_t)row * DD))[lane] = __floats2half2_rn(di * ox, di * oy);
}

// y[i] = dinv_i * ( sum_{j in nbr} zp[j] + zp[i] );  zp is premultiplied fp16.
// One wave per node, halves take contiguous csr sub-ranges, 8 edges in flight
// per half (16 row-loads/wave). Pure adds in fp32.
__global__ void k_aggregate(const __half* __restrict__ zp,
                            __half* __restrict__ Ah,
                            const int2* __restrict__ startdeg,
                            const int* __restrict__ csr,
                            const float* __restrict__ dinv) {
  int node = blockIdx.x * 4 + (threadIdx.x >> 6);
  int lane = threadIdx.x & 63;
  int half = lane >> 5;
  int l32  = lane & 31;
  int2 sd = startdeg[node];
  int mid = sd.x + (sd.y >> 1);
  int k   = half ? mid : sd.x;
  int end = half ? (sd.x + sd.y) : mid;
  float di = dinv[node];
  const H4* zr = (const H4*)zp;            // row stride = 32 H4
  float4 acc = make_float4(0.f, 0.f, 0.f, 0.f);
  for (; k + 8 <= end; k += 8) {
    int j[8];
    #pragma unroll
    for (int u = 0; u < 8; ++u) j[u] = csr[k + u];
    H4 a[8];
    #pragma unroll
    for (int u = 0; u < 8; ++u) a[u] = zr[(size_t)j[u] * 32 + l32];
    #pragma unroll
    for (int u = 0; u < 8; ++u) {
      float2 fa = __half22float2(a[u].a), fb = __half22float2(a[u].b);
      acc.x += fa.x; acc.y += fa.y; acc.z += fb.x; acc.w += fb.y;
    }
  }
  for (; k < end; ++k) {
    int j0 = csr[k];
    H4 a0 = zr[(size_t)j0 * 32 + l32];
    float2 fa = __half22float2(a0.a), fb = __half22float2(a0.b);
    acc.x += fa.x; acc.y += fa.y; acc.z += fb.x; acc.w += fb.y;
  }
  acc.x += __shfl_xor(acc.x, 32, 64);
  acc.y += __shfl_xor(acc.y, 32, 64);
  acc.z += __shfl_xor(acc.z, 32, 64);
  acc.w += __shfl_xor(acc.w, 32, 64);
  if (half == 0) {
    H4 zs = zr[(size_t)node * 32 + l32];   // zp[i]
    float2 za = __half22float2(zs.a), zb2 = __half22float2(zs.b);
    H4 o;
    o.a = __floats2half2_rn((acc.x + za.x) * di, (acc.y + za.y) * di);
    o.b = __floats2half2_rn((acc.z + zb2.x) * di, (acc.w + zb2.y) * di);
    ((H4*)Ah)[(size_t)node * 64 + l32] = o;
  }
}

// out = leaky( Ah(N x 256) @ WhT^T + bias2 ) via mfma_f32_16x16x32_f16.
// LDS-free: 4 waves/block, each wave 32 rows x 128 cols (16 tiles of 16x16).
__global__ __launch_bounds__(256) void k_gemm(
    const __half* __restrict__ Ah, const __half* __restrict__ WhT,
    const float* __restrict__ bias2, float* __restrict__ out) {
  const int tid = threadIdx.x;
  const int w  = tid >> 6;
  const int l  = tid & 63;
  const int lm = l & 15;
  const int lk = l >> 4;
  const int row0 = blockIdx.x * 128 + w * 32;

  int rA0 = row0 + lm;
  int rA1 = row0 + 16 + lm;
  if (rA0 >= NN) rA0 = NN - 1;   // clamp; stores are guarded
  if (rA1 >= NN) rA1 = NN - 1;

  f32x4 acc0[8], acc1[8];
  #pragma unroll
  for (int c = 0; c < 8; ++c) {
    acc0[c] = (f32x4)(0.f);
    acc1[c] = (f32x4)(0.f);
  }

  const __half* a0p = Ah + (size_t)rA0 * 256 + lk * 8;
  const __half* a1p = Ah + (size_t)rA1 * 256 + lk * 8;
  const __half* bp  = WhT + (size_t)lm * 256 + lk * 8;

  #pragma unroll
  for (int ks = 0; ks < 8; ++ks) {
    f16x8 a0 = *(const f16x8*)(a0p + ks * 32);
    f16x8 a1 = *(const f16x8*)(a1p + ks * 32);
    #pragma unroll
    for (int c = 0; c < 8; ++c) {
      f16x8 b = *(const f16x8*)(bp + (size_t)c * 16 * 256 + ks * 32);
      acc0[c] = __builtin_amdgcn_mfma_f32_16x16x32_f16(a0, b, acc0[c], 0, 0, 0);
      acc1[c] = __builtin_amdgcn_mfma_f32_16x16x32_f16(a1, b, acc1[c], 0, 0, 0);
    }
  }

  int orow0 = row0 + lk * 4;
  int orow1 = row0 + 16 + lk * 4;
  #pragma unroll
  for (int c = 0; c < 8; ++c) {
    int col = c * 16 + lm;
    float bs = bias2[col];
    #pragma unroll
    for (int r = 0; r < 4; ++r) {
      int g0 = orow0 + r;
      if (g0 < NN) {
        float v = acc0[c][r] + bs;
        out[(size_t)g0 * 128 + col] = (v >= 0.f) ? v : SLOPE * v;
      }
      int g1 = orow1 + r;
      if (g1 < NN) {
        float v = acc1[c][r] + bs;
        out[(size_t)g1 * 128 + col] = (v >= 0.f) ? v : SLOPE * v;
      }
    }
  }
}

extern "C" void kernel_launch(void* const* d_in, const int* in_sizes, int n_in,
                              void* d_out, int out_size, void* d_ws, size_t ws_size,
                              hipStream_t stream) {
  const float* x     = (const float*)d_in[0];
  const int*   ei    = (const int*)d_in[1];
  const float* W     = (const float*)d_in[2];
  const float* b     = (const float*)d_in[3];
  const float* gamma = (const float*)d_in[4];
  const float* beta  = (const float*)d_in[5];
  const float* mean  = (const float*)d_in[6];
  const float* var   = (const float*)d_in[7];
  const float* rsW   = (const float*)d_in[8];
  const float* rsb   = (const float*)d_in[9];
  float* out = (float*)d_out;
  const int* src = ei;         // edge_index[0]
  const int* dst = ei + EE;    // edge_index[1]

  // workspace carve-up (~94 MB)
  __half* Ah       = (__half*)d_ws;                     // NN*256 f16
  __half* zp       = Ah + (size_t)NN * 256;             // NN*128 f16
  int2*   startdeg = (int2*)(zp + (size_t)NN * DD);     // NN int2
  float*  dinv     = (float*)(startdeg + NN);           // NN f32
  int*    gcur     = (int*)(dinv + NN);                 // NBKT (pad 128)
  int*    pairs    = gcur + 128;                        // NBKT*CAPP
  int*    csr      = pairs + NBKT * CAPP;               // NBKT*CAPP
  __half* WhT      = (__half*)(csr + NBKT * CAPP);      // 128*256 f16
  float*  bias2    = (float*)(WhT + 128 * 256);         // DD f32

  k_prep<<<129, 256, 0, stream>>>(W, rsW, b, rsb, WhT, bias2, gcur);
  k_binA<<<(EE + EPB - 1) / EPB, 256, 0, stream>>>(src, dst, gcur, pairs);
  k_binB<<<NBKT, 1024, 0, stream>>>(gcur, pairs, csr, startdeg, dinv);
  k_norm_bn<<<NN / 4, 256, 0, stream>>>(x, gamma, beta, mean, var, dinv, Ah, zp);
  k_aggregate<<<NN / 4, 256, 0, stream>>>(zp, Ah, startdeg, csr, dinv);
  k_gemm<<<(NN + 127) / 128, 256, 0, stream>>>(Ah, WhT, bias2, out);
}

// Round 8
// 280.956 us; speedup vs baseline: 1.1020x; 1.1020x over previous
//
#include <hip/hip_runtime.h>
#include <hip/hip_fp16.h>

// GNN fused pipeline on MI355X (gfx950).
//   CSR by dst via two-level counting sort (binA coarse, binB per-bucket)
//   norm_bn: z = BN(l2normalize(x)) -> Ah cols 128..255 (fp16)
//            zp = dinv*z            -> dense fp16 gather array
//   aggregate: y[i] = dinv_i*(sum_j zp[j] + zp[i]) -> Ah cols 0..127
//   out = leaky( Ah @ WhT^T + bias2 )  fp16 MFMA 16x16x32, B staged in LDS

#define NN 100000
#define DD 128
#define EE 1600000
#define BN_EPS 1e-5f
#define SLOPE 0.01f

#define NBKT 98          // ceil(NN / 1024)
#define BWID 1024        // nodes per bucket (dst >> 10)
#define CAPP 20480       // slack capacity per bucket (mean 16327, sd ~128)
#define EPB  4096        // edges per binA block -> 391 blocks

struct __align__(8) H4 { __half2 a, b; };   // 4 halves = 8 bytes

typedef _Float16 f16x8 __attribute__((ext_vector_type(8)));
typedef float    f32x4 __attribute__((ext_vector_type(4)));

// blocks 0..127: WhT[n][k] = fp16 of [W;rs_W][k][n]; block 128: bias2 + gcur init
__global__ void k_prep(const float* __restrict__ W, const float* __restrict__ rsW,
                       const float* __restrict__ b, const float* __restrict__ rb,
                       __half* __restrict__ WhT, float* __restrict__ bias2,
                       int* __restrict__ gcur) {
  int blk = blockIdx.x, t = threadIdx.x;
  if (blk == 128) {
    if (t < DD) bias2[t] = b[t] + rb[t];
    if (t < NBKT) gcur[t] = t * CAPP;
    return;
  }
  float v = (t < 128) ? W[t * 128 + blk] : rsW[(t - 128) * 128 + blk];
  WhT[blk * 256 + t] = __float2half(v);
}

// Phase A (R5 form): coarse binning; wave-parity-split LDS histograms; one
// global atomic per (block,bucket). pairs[] entry: (local_dst << 17) | src
__global__ __launch_bounds__(256) void k_binA(const int* __restrict__ src,
                                              const int* __restrict__ dst,
                                              int* __restrict__ gcur,
                                              int* __restrict__ pairs) {
  __shared__ int hist[2][NBKT];
  __shared__ int cur[2][NBKT];
  int t = threadIdx.x;
  int w2 = (t >> 6) & 1;
  if (t < NBKT) { hist[0][t] = 0; hist[1][t] = 0; }
  __syncthreads();
  int e0 = blockIdx.x * EPB;
  #pragma unroll 4
  for (int i = 0; i < EPB / 256; ++i) {
    int e = e0 + i * 256 + t;
    if (e < EE) atomicAdd(&hist[w2][dst[e] >> 10], 1);
  }
  __syncthreads();
  if (t < NBKT) {
    int h0 = hist[0][t], h1 = hist[1][t];
    int b0 = atomicAdd(&gcur[t], h0 + h1);
    cur[0][t] = b0;
    cur[1][t] = b0 + h0;
  }
  __syncthreads();
  #pragma unroll 4
  for (int i = 0; i < EPB / 256; ++i) {
    int e = e0 + i * 256 + t;
    if (e < EE) {
      int d = dst[e], s = src[e];
      int bk = d >> 10;
      int r = atomicAdd(&cur[w2][bk], 1);
      pairs[r] = ((d & 1023) << 17) | s;
    }
  }
}

// Phase B: one block per bucket; LDS histogram + scan -> dinv, startdeg; csr
// scatter within the bucket's exclusive region.
__global__ __launch_bounds__(1024) void k_binB(const int* __restrict__ gcur,
                                               const int* __restrict__ pairs,
                                               int* __restrict__ csr,
                                               int2* __restrict__ startdeg,
                                               float* __restrict__ dinv) {
  __shared__ int hist[BWID];
  __shared__ int excl[BWID];
  __shared__ int wsum[16];
  int b = blockIdx.x, t = threadIdx.x;
  hist[t] = 0;
  __syncthreads();
  int pbase = b * CAPP;
  int cnt = gcur[b] - pbase;
  for (int i = t; i < cnt; i += BWID)
    atomicAdd(&hist[pairs[pbase + i] >> 17], 1);
  __syncthreads();
  int v = hist[t];
  int lane = t & 63, w = t >> 6;
  int incl = v;
  #pragma unroll
  for (int off = 1; off < 64; off <<= 1) {
    int n = __shfl_up(incl, off, 64);
    if (lane >= off) incl += n;
  }
  if (lane == 63) wsum[w] = incl;
  __syncthreads();
  if (t < 16) {
    int orig = wsum[t];
    int s = orig;
    #pragma unroll
    for (int off = 1; off < 16; off <<= 1) {
      int n = __shfl_up(s, off, 64);
      if (t >= off) s += n;
    }
    wsum[t] = s - orig;
  }
  __syncthreads();
  int myexcl = (incl - v) + wsum[w];
  excl[t] = myexcl;
  int node = b * BWID + t;
  if (node < NN) {
    dinv[node] = rsqrtf((float)(v + 1));               // +1 self-loop
    startdeg[node] = make_int2(pbase + myexcl, v);
  }
  __syncthreads();
  for (int i = t; i < cnt; i += BWID) {
    int p = pairs[pbase + i];
    int pos = atomicAdd(&excl[p >> 17], 1);
    csr[pbase + pos] = p & 0x1FFFF;
  }
}

// fused row L2-normalize + BatchNorm(eval); one 64-lane wave per row.
// Writes fp16 z into Ah cols 128..255 and zp = dinv*z (dense fp16).
__global__ void k_norm_bn(const float* __restrict__ x,
                          const float* __restrict__ gamma,
                          const float* __restrict__ beta,
                          const float* __restrict__ mean,
                          const float* __restrict__ var,
                          const float* __restrict__ dinv,
                          __half* __restrict__ Ah, __half* __restrict__ zp) {
  int row = blockIdx.x * 4 + (threadIdx.x >> 6);
  int lane = threadIdx.x & 63;
  if (row >= NN) return;
  float2 v = ((const float2*)(x + (size_t)row * DD))[lane];
  float ss = v.x * v.x + v.y * v.y;
  #pragma unroll
  for (int off = 32; off > 0; off >>= 1) ss += __shfl_xor(ss, off);
  float s = 1.0f / fmaxf(sqrtf(ss), 1e-12f);
  float di = dinv[row];
  int c = lane * 2;
  float g0 = gamma[c]     * rsqrtf(var[c]     + BN_EPS);
  float g1 = gamma[c + 1] * rsqrtf(var[c + 1] + BN_EPS);
  float ox = (v.x * s - mean[c])     * g0 + beta[c];
  float oy = (v.y * s - mean[c + 1]) * g1 + beta[c + 1];
  ((__half2*)(Ah + (size_t)row * 256 + 128))[lane] = __floats2half2_rn(ox, oy);
  ((__half2*)(zp + (size_t)row * DD))[lane] = __floats2half2_rn(di * ox, di * oy);
}

// y[i] = dinv_i * ( sum_j zp[j] + zp[i] );  zp premultiplied fp16, dense.
// R5 loop shape: one wave/node, halves interleave by parity, 4 edges per half
// unrolled (8 row-loads in flight per wave), 2-stride tail.
__global__ void k_aggregate(const __half* __restrict__ zp,
                            __half* __restrict__ Ah,
                            const int2* __restrict__ startdeg,
                            const int* __restrict__ csr,
                            const float* __restrict__ dinv) {
  int node = blockIdx.x * 4 + (threadIdx.x >> 6);
  int lane = threadIdx.x & 63;
  int half = lane >> 5;
  int l32  = lane & 31;
  int2 sd = startdeg[node];
  int beg = sd.x, end = sd.x + sd.y;
  float di = dinv[node];
  const H4* zr = (const H4*)zp;            // row stride = 32 H4
  float4 acc = make_float4(0.f, 0.f, 0.f, 0.f);
  int k = beg + half;
  for (; k + 6 < end; k += 8) {            // 4 edges per half per iter
    int j0 = csr[k], j1 = csr[k + 2], j2 = csr[k + 4], j3 = csr[k + 6];
    H4 a0 = zr[(size_t)j0 * 32 + l32];
    H4 a1 = zr[(size_t)j1 * 32 + l32];
    H4 a2 = zr[(size_t)j2 * 32 + l32];
    H4 a3 = zr[(size_t)j3 * 32 + l32];
    float2 f0a = __half22float2(a0.a), f0b = __half22float2(a0.b);
    float2 f1a = __half22float2(a1.a), f1b = __half22float2(a1.b);
    float2 f2a = __half22float2(a2.a), f2b = __half22float2(a2.b);
    float2 f3a = __half22float2(a3.a), f3b = __half22float2(a3.b);
    acc.x += (f0a.x + f1a.x) + (f2a.x + f3a.x);
    acc.y += (f0a.y + f1a.y) + (f2a.y + f3a.y);
    acc.z += (f0b.x + f1b.x) + (f2b.x + f3b.x);
    acc.w += (f0b.y + f1b.y) + (f2b.y + f3b.y);
  }
  for (; k < end; k += 2) {
    int j0 = csr[k];
    H4 a0 = zr[(size_t)j0 * 32 + l32];
    float2 fa = __half22float2(a0.a), fb = __half22float2(a0.b);
    acc.x += fa.x; acc.y += fa.y; acc.z += fb.x; acc.w += fb.y;
  }
  acc.x += __shfl_xor(acc.x, 32, 64);
  acc.y += __shfl_xor(acc.y, 32, 64);
  acc.z += __shfl_xor(acc.z, 32, 64);
  acc.w += __shfl_xor(acc.w, 32, 64);
  if (half == 0) {
    H4 zs = zr[(size_t)node * 32 + l32];   // zp[i]
    float2 za = __half22float2(zs.a), zb2 = __half22float2(zs.b);
    H4 o;
    o.a = __floats2half2_rn((acc.x + za.x) * di, (acc.y + za.y) * di);
    o.b = __floats2half2_rn((acc.z + zb2.x) * di, (acc.w + zb2.y) * di);
    ((H4*)Ah)[(size_t)node * 64 + l32] = o;
  }
}

// out = leaky( Ah(N x 256) @ WhT^T + bias2 ) via mfma_f32_16x16x32_f16.
// 512 threads = 8 waves, each wave 32 rows x 128 cols. WhT (64 KB) staged in
// LDS once per block with XOR swizzle (byte ^= (row&7)<<4; XOR touches only
// bits 4..6, within each 512B row; on read row&7 == lm&7 so the permutations
// match). Lane bank-group = lk ^ (lm&7): uniform 8 lanes / 4-bank group.
__global__ __launch_bounds__(512, 2) void k_gemm(
    const __half* __restrict__ Ah, const __half* __restrict__ WhT,
    const float* __restrict__ bias2, float* __restrict__ out) {
  __shared__ __align__(16) char Bs[65536];
  const int tid = threadIdx.x;
  const int w  = tid >> 6;
  const int l  = tid & 63;
  const int lm = l & 15;
  const int lk = l >> 4;
  const int row0 = blockIdx.x * 256 + w * 32;

  int rA0 = row0 + lm;
  int rA1 = row0 + 16 + lm;
  if (rA0 >= NN) rA0 = NN - 1;   // clamp; stores are guarded
  if (rA1 >= NN) rA1 = NN - 1;

  // A-fragments: issue all 16 global loads up front, hold in regs
  const __half* a0p = Ah + (size_t)rA0 * 256 + lk * 8;
  const __half* a1p = Ah + (size_t)rA1 * 256 + lk * 8;
  f16x8 a0[8], a1[8];
  #pragma unroll
  for (int ks = 0; ks < 8; ++ks) {
    a0[ks] = *(const f16x8*)(a0p + ks * 32);
    a1[ks] = *(const f16x8*)(a1p + ks * 32);
  }

  // stage WhT -> LDS with XOR swizzle (write side)
  #pragma unroll
  for (int i = 0; i < 8; ++i) {
    int idx = tid + i * 512;              // float4 index over 64 KB
    int byte = idx * 16;
    int swz = byte ^ (((byte >> 9) & 7) << 4);
    *(float4*)(Bs + swz) = ((const float4*)WhT)[idx];
  }
  __syncthreads();

  f32x4 acc0[8], acc1[8];
  #pragma unroll
  for (int c = 0; c < 8; ++c) {
    acc0[c] = (f32x4)(0.f);
    acc1[c] = (f32x4)(0.f);
  }

  #pragma unroll
  for (int ks = 0; ks < 8; ++ks) {
    #pragma unroll
    for (int c = 0; c < 8; ++c) {
      int byte = (c * 16 + lm) * 512 + lk * 16 + ks * 64;
      f16x8 b = *(const f16x8*)(Bs + (byte ^ ((lm & 7) << 4)));
      acc0[c] = __builtin_amdgcn_mfma_f32_16x16x32_f16(a0[ks], b, acc0[c], 0, 0, 0);
      acc1[c] = __builtin_amdgcn_mfma_f32_16x16x32_f16(a1[ks], b, acc1[c], 0, 0, 0);
    }
  }

  int orow0 = row0 + lk * 4;
  int orow1 = row0 + 16 + lk * 4;
  #pragma unroll
  for (int c = 0; c < 8; ++c) {
    int col = c * 16 + lm;
    float bs = bias2[col];
    #pragma unroll
    for (int r = 0; r < 4; ++r) {
      int g0 = orow0 + r;
      if (g0 < NN) {
        float v = acc0[c][r] + bs;
        out[(size_t)g0 * 128 + col] = (v >= 0.f) ? v : SLOPE * v;
      }
      int g1 = orow1 + r;
      if (g1 < NN) {
        float v = acc1[c][r] + bs;
        out[(size_t)g1 * 128 + col] = (v >= 0.f) ? v : SLOPE * v;
      }
    }
  }
}

extern "C" void kernel_launch(void* const* d_in, const int* in_sizes, int n_in,
                              void* d_out, int out_size, void* d_ws, size_t ws_size,
                              hipStream_t stream) {
  const float* x     = (const float*)d_in[0];
  const int*   ei    = (const int*)d_in[1];
  const float* W     = (const float*)d_in[2];
  const float* b     = (const float*)d_in[3];
  const float* gamma = (const float*)d_in[4];
  const float* beta  = (const float*)d_in[5];
  const float* mean  = (const float*)d_in[6];
  const float* var   = (const float*)d_in[7];
  const float* rsW   = (const float*)d_in[8];
  const float* rsb   = (const float*)d_in[9];
  float* out = (float*)d_out;
  const int* src = ei;         // edge_index[0]
  const int* dst = ei + EE;    // edge_index[1]

  // workspace carve-up (~94 MB)
  __half* Ah       = (__half*)d_ws;                     // NN*256 f16
  __half* zp       = Ah + (size_t)NN * 256;             // NN*128 f16
  int2*   startdeg = (int2*)(zp + (size_t)NN * DD);     // NN int2
  float*  dinv     = (float*)(startdeg + NN);           // NN f32
  int*    gcur     = (int*)(dinv + NN);                 // NBKT (pad 128)
  int*    pairs    = gcur + 128;                        // NBKT*CAPP
  int*    csr      = pairs + NBKT * CAPP;               // NBKT*CAPP
  __half* WhT      = (__half*)(csr + NBKT * CAPP);      // 128*256 f16
  float*  bias2    = (float*)(WhT + 128 * 256);         // DD f32

  k_prep<<<129, 256, 0, stream>>>(W, rsW, b, rsb, WhT, bias2, gcur);
  k_binA<<<(EE + EPB - 1) / EPB, 256, 0, stream>>>(src, dst, gcur, pairs);
  k_binB<<<NBKT, 1024, 0, stream>>>(gcur, pairs, csr, startdeg, dinv);
  k_norm_bn<<<NN / 4, 256, 0, stream>>>(x, gamma, beta, mean, var, dinv, Ah, zp);
  k_aggregate<<<NN / 4, 256, 0, stream>>>(zp, Ah, startdeg, csr, dinv);
  k_gemm<<<(NN + 255) / 256, 512, 0, stream>>>(Ah, WhT, bias2, out);
}

// Round 9
// 272.587 us; speedup vs baseline: 1.1359x; 1.0307x over previous
//
#include <hip/hip_runtime.h>
#include <hip/hip_fp16.h>

// GNN fused pipeline on MI355X (gfx950).
//   CSR by dst via two-level counting sort (binA coarse [+prep], binB per-bucket)
//   norm_bn: z = BN(l2normalize(x)) -> Ah cols 128..255 (fp16)
//            zp = dinv*z            -> dense fp16 gather array
//   aggregate: y[i] = dinv_i*(sum_j zp[j] + zp[i]) -> Ah cols 0..127
//              (one node per 32-lane half: 16 row-loads in flight per wave)
//   out = leaky( Ah @ WhT^T + bias2 )  fp16 MFMA 16x16x32, B staged in LDS

#define NN 100000
#define DD 128
#define EE 1600000
#define BN_EPS 1e-5f
#define SLOPE 0.01f

#define NBKT 98          // ceil(NN / 1024)
#define BWID 1024        // nodes per bucket (dst >> 10)
#define CAPP 20480       // slack capacity per bucket (mean 16327, sd ~128)
#define EPB  4096        // edges per binA block
#define EBLK 391         // (EE + EPB - 1) / EPB

struct __align__(8) H4 { __half2 a, b; };   // 4 halves = 8 bytes

typedef _Float16 f16x8 __attribute__((ext_vector_type(8)));
typedef float    f32x4 __attribute__((ext_vector_type(4)));

// Phase A: blocks 0..390 coarse-bin edges (wave-parity LDS histograms, one
// global atomic per (block,bucket), relative cursors; gcur pre-zeroed by
// memset). Blocks 391..519: WhT transpose + bias (absorbed k_prep).
// pairs[] entry: (local_dst << 17) | src
__global__ __launch_bounds__(256) void k_binA(const int* __restrict__ src,
                                              const int* __restrict__ dst,
                                              int* __restrict__ gcur,
                                              int* __restrict__ pairs,
                                              const float* __restrict__ W,
                                              const float* __restrict__ rsW,
                                              const float* __restrict__ b,
                                              const float* __restrict__ rb,
                                              __half* __restrict__ WhT,
                                              float* __restrict__ bias2) {
  int t = threadIdx.x;
  if (blockIdx.x >= EBLK) {
    int blk = blockIdx.x - EBLK;
    if (blk == 128) {
      if (t < DD) bias2[t] = b[t] + rb[t];
    } else {
      float v = (t < 128) ? W[t * 128 + blk] : rsW[(t - 128) * 128 + blk];
      WhT[blk * 256 + t] = __float2half(v);
    }
    return;
  }
  __shared__ int hist[2][NBKT];
  __shared__ int cur[2][NBKT];
  int w2 = (t >> 6) & 1;
  if (t < NBKT) { hist[0][t] = 0; hist[1][t] = 0; }
  __syncthreads();
  int e0 = blockIdx.x * EPB;
  #pragma unroll 4
  for (int i = 0; i < EPB / 256; ++i) {
    int e = e0 + i * 256 + t;
    if (e < EE) atomicAdd(&hist[w2][dst[e] >> 10], 1);
  }
  __syncthreads();
  if (t < NBKT) {
    int h0 = hist[0][t], h1 = hist[1][t];
    int b0 = atomicAdd(&gcur[t], h0 + h1);   // relative base within bucket
    cur[0][t] = b0;
    cur[1][t] = b0 + h0;
  }
  __syncthreads();
  #pragma unroll 4
  for (int i = 0; i < EPB / 256; ++i) {
    int e = e0 + i * 256 + t;
    if (e < EE) {
      int d = dst[e], s = src[e];
      int bk = d >> 10;
      int r = atomicAdd(&cur[w2][bk], 1);
      pairs[(size_t)bk * CAPP + r] = ((d & 1023) << 17) | s;
    }
  }
}

// Phase B: one block per bucket; LDS histogram + scan -> dinv, startdeg; csr
// scatter within the bucket's exclusive region. gcur[b] is now a COUNT.
__global__ __launch_bounds__(1024) void k_binB(const int* __restrict__ gcur,
                                               const int* __restrict__ pairs,
                                               int* __restrict__ csr,
                                               int2* __restrict__ startdeg,
                                               float* __restrict__ dinv) {
  __shared__ int hist[BWID];
  __shared__ int excl[BWID];
  __shared__ int wsum[16];
  int b = blockIdx.x, t = threadIdx.x;
  hist[t] = 0;
  __syncthreads();
  int pbase = b * CAPP;
  int cnt = gcur[b];
  for (int i = t; i < cnt; i += BWID)
    atomicAdd(&hist[pairs[pbase + i] >> 17], 1);
  __syncthreads();
  int v = hist[t];
  int lane = t & 63, w = t >> 6;
  int incl = v;
  #pragma unroll
  for (int off = 1; off < 64; off <<= 1) {
    int n = __shfl_up(incl, off, 64);
    if (lane >= off) incl += n;
  }
  if (lane == 63) wsum[w] = incl;
  __syncthreads();
  if (t < 16) {
    int orig = wsum[t];
    int s = orig;
    #pragma unroll
    for (int off = 1; off < 16; off <<= 1) {
      int n = __shfl_up(s, off, 64);
      if (t >= off) s += n;
    }
    wsum[t] = s - orig;
  }
  __syncthreads();
  int myexcl = (incl - v) + wsum[w];
  excl[t] = myexcl;
  int node = b * BWID + t;
  if (node < NN) {
    dinv[node] = rsqrtf((float)(v + 1));               // +1 self-loop
    startdeg[node] = make_int2(pbase + myexcl, v);
  }
  __syncthreads();
  for (int i = t; i < cnt; i += BWID) {
    int p = pairs[pbase + i];
    int pos = atomicAdd(&excl[p >> 17], 1);
    csr[pbase + pos] = p & 0x1FFFF;
  }
}

// fused row L2-normalize + BatchNorm(eval); one 64-lane wave per row.
// Writes fp16 z into Ah cols 128..255 and zp = dinv*z (dense fp16).
__global__ void k_norm_bn(const float* __restrict__ x,
                          const float* __restrict__ gamma,
                          const float* __restrict__ beta,
                          const float* __restrict__ mean,
                          const float* __restrict__ var,
                          const float* __restrict__ dinv,
                          __half* __restrict__ Ah, __half* __restrict__ zp) {
  int row = blockIdx.x * 4 + (threadIdx.x >> 6);
  int lane = threadIdx.x & 63;
  if (row >= NN) return;
  float2 v = ((const float2*)(x + (size_t)row * DD))[lane];
  float ss = v.x * v.x + v.y * v.y;
  #pragma unroll
  for (int off = 32; off > 0; off >>= 1) ss += __shfl_xor(ss, off);
  float s = 1.0f / fmaxf(sqrtf(ss), 1e-12f);
  float di = dinv[row];
  int c = lane * 2;
  float g0 = gamma[c]     * rsqrtf(var[c]     + BN_EPS);
  float g1 = gamma[c + 1] * rsqrtf(var[c + 1] + BN_EPS);
  float ox = (v.x * s - mean[c])     * g0 + beta[c];
  float oy = (v.y * s - mean[c + 1]) * g1 + beta[c + 1];
  ((__half2*)(Ah + (size_t)row * 256 + 128))[lane] = __floats2half2_rn(ox, oy);
  ((__half2*)(zp + (size_t)row * DD))[lane] = __floats2half2_rn(di * ox, di * oy);
}

// y[i] = dinv_i * ( sum_j zp[j] + zp[i] );  zp premultiplied fp16, dense.
// Each 32-lane half owns ONE node and its full contiguous edge list:
// 8-deep unroll per half => 16 row-loads in flight per wave, no cross-half
// reduce, both halves write their own 256B output row.
__global__ void k_aggregate(const __half* __restrict__ zp,
                            __half* __restrict__ Ah,
                            const int2* __restrict__ startdeg,
                            const int* __restrict__ csr,
                            const float* __restrict__ dinv) {
  int lane = threadIdx.x & 63;
  int half = lane >> 5;
  int l32  = lane & 31;
  int node = blockIdx.x * 8 + (threadIdx.x >> 6) * 2 + half;
  int2 sd = startdeg[node];
  int k = sd.x, end = sd.x + sd.y;
  float di = dinv[node];
  const H4* zr = (const H4*)zp;            // row stride = 32 H4
  float4 acc = make_float4(0.f, 0.f, 0.f, 0.f);
  for (; k + 8 <= end; k += 8) {
    int j[8];
    #pragma unroll
    for (int u = 0; u < 8; ++u) j[u] = csr[k + u];
    H4 a[8];
    #pragma unroll
    for (int u = 0; u < 8; ++u) a[u] = zr[(size_t)j[u] * 32 + l32];
    #pragma unroll
    for (int u = 0; u < 8; ++u) {
      float2 fa = __half22float2(a[u].a), fb = __half22float2(a[u].b);
      acc.x += fa.x; acc.y += fa.y; acc.z += fb.x; acc.w += fb.y;
    }
  }
  if (k + 4 <= end) {
    int j[4];
    #pragma unroll
    for (int u = 0; u < 4; ++u) j[u] = csr[k + u];
    H4 a[4];
    #pragma unroll
    for (int u = 0; u < 4; ++u) a[u] = zr[(size_t)j[u] * 32 + l32];
    #pragma unroll
    for (int u = 0; u < 4; ++u) {
      float2 fa = __half22float2(a[u].a), fb = __half22float2(a[u].b);
      acc.x += fa.x; acc.y += fa.y; acc.z += fb.x; acc.w += fb.y;
    }
    k += 4;
  }
  for (; k < end; ++k) {
    int j0 = csr[k];
    H4 a0 = zr[(size_t)j0 * 32 + l32];
    float2 fa = __half22float2(a0.a), fb = __half22float2(a0.b);
    acc.x += fa.x; acc.y += fa.y; acc.z += fb.x; acc.w += fb.y;
  }
  H4 zs = zr[(size_t)node * 32 + l32];     // zp[i] self-term
  float2 za = __half22float2(zs.a), zb2 = __half22float2(zs.b);
  H4 o;
  o.a = __floats2half2_rn((acc.x + za.x) * di, (acc.y + za.y) * di);
  o.b = __floats2half2_rn((acc.z + zb2.x) * di, (acc.w + zb2.y) * di);
  ((H4*)Ah)[(size_t)node * 64 + l32] = o;
}

// out = leaky( Ah(N x 256) @ WhT^T + bias2 ) via mfma_f32_16x16x32_f16.
// 512 threads = 8 waves, each wave 32 rows x 128 cols. WhT (64 KB) staged in
// LDS once per block with XOR swizzle (byte ^= (row&7)<<4; same permutation
// on write and read). Lane bank-group = lk ^ (lm&7): uniform spread.
__global__ __launch_bounds__(512, 2) void k_gemm(
    const __half* __restrict__ Ah, const __half* __restrict__ WhT,
    const float* __restrict__ bias2, float* __restrict__ out) {
  __shared__ __align__(16) char Bs[65536];
  const int tid = threadIdx.x;
  const int w  = tid >> 6;
  const int l  = tid & 63;
  const int lm = l & 15;
  const int lk = l >> 4;
  const int row0 = blockIdx.x * 256 + w * 32;

  int rA0 = row0 + lm;
  int rA1 = row0 + 16 + lm;
  if (rA0 >= NN) rA0 = NN - 1;   // clamp; stores are guarded
  if (rA1 >= NN) rA1 = NN - 1;

  // A-fragments: issue all 16 global loads up front, hold in regs
  const __half* a0p = Ah + (size_t)rA0 * 256 + lk * 8;
  const __half* a1p = Ah + (size_t)rA1 * 256 + lk * 8;
  f16x8 a0[8], a1[8];
  #pragma unroll
  for (int ks = 0; ks < 8; ++ks) {
    a0[ks] = *(const f16x8*)(a0p + ks * 32);
    a1[ks] = *(const f16x8*)(a1p + ks * 32);
  }

  // stage WhT -> LDS with XOR swizzle (write side)
  #pragma unroll
  for (int i = 0; i < 8; ++i) {
    int idx = tid + i * 512;              // float4 index over 64 KB
    int byte = idx * 16;
    int swz = byte ^ (((byte >> 9) & 7) << 4);
    *(float4*)(Bs + swz) = ((const float4*)WhT)[idx];
  }
  __syncthreads();

  f32x4 acc0[8], acc1[8];
  #pragma unroll
  for (int c = 0; c < 8; ++c) {
    acc0[c] = (f32x4)(0.f);
    acc1[c] = (f32x4)(0.f);
  }

  #pragma unroll
  for (int ks = 0; ks < 8; ++ks) {
    #pragma unroll
    for (int c = 0; c < 8; ++c) {
      int byte = (c * 16 + lm) * 512 + lk * 16 + ks * 64;
      f16x8 b = *(const f16x8*)(Bs + (byte ^ ((lm & 7) << 4)));
      acc0[c] = __builtin_amdgcn_mfma_f32_16x16x32_f16(a0[ks], b, acc0[c], 0, 0, 0);
      acc1[c] = __builtin_amdgcn_mfma_f32_16x16x32_f16(a1[ks], b, acc1[c], 0, 0, 0);
    }
  }

  int orow0 = row0 + lk * 4;
  int orow1 = row0 + 16 + lk * 4;
  #pragma unroll
  for (int c = 0; c < 8; ++c) {
    int col = c * 16 + lm;
    float bs = bias2[col];
    #pragma unroll
    for (int r = 0; r < 4; ++r) {
      int g0 = orow0 + r;
      if (g0 < NN) {
        float v = acc0[c][r] + bs;
        out[(size_t)g0 * 128 + col] = (v >= 0.f) ? v : SLOPE * v;
      }
      int g1 = orow1 + r;
      if (g1 < NN) {
        float v = acc1[c][r] + bs;
        out[(size_t)g1 * 128 + col] = (v >= 0.f) ? v : SLOPE * v;
      }
    }
  }
}

extern "C" void kernel_launch(void* const* d_in, const int* in_sizes, int n_in,
                              void* d_out, int out_size, void* d_ws, size_t ws_size,
                              hipStream_t stream) {
  const float* x     = (const float*)d_in[0];
  const int*   ei    = (const int*)d_in[1];
  const float* W     = (const float*)d_in[2];
  const float* b     = (const float*)d_in[3];
  const float* gamma = (const float*)d_in[4];
  const float* beta  = (const float*)d_in[5];
  const float* mean  = (const float*)d_in[6];
  const float* var   = (const float*)d_in[7];
  const float* rsW   = (const float*)d_in[8];
  const float* rsb   = (const float*)d_in[9];
  float* out = (float*)d_out;
  const int* src = ei;         // edge_index[0]
  const int* dst = ei + EE;    // edge_index[1]

  // workspace carve-up (~94 MB)
  __half* Ah       = (__half*)d_ws;                     // NN*256 f16
  __half* zp       = Ah + (size_t)NN * 256;             // NN*128 f16
  int2*   startdeg = (int2*)(zp + (size_t)NN * DD);     // NN int2
  float*  dinv     = (float*)(startdeg + NN);           // NN f32
  int*    gcur     = (int*)(dinv + NN);                 // NBKT (pad 128)
  int*    pairs    = gcur + 128;                        // NBKT*CAPP
  int*    csr      = pairs + NBKT * CAPP;               // NBKT*CAPP
  __half* WhT      = (__half*)(csr + NBKT * CAPP);      // 128*256 f16
  float*  bias2    = (float*)(WhT + 128 * 256);         // DD f32

  hipMemsetAsync(gcur, 0, 128 * sizeof(int), stream);
  k_binA<<<EBLK + 129, 256, 0, stream>>>(src, dst, gcur, pairs,
                                         W, rsW, b, rsb, WhT, bias2);
  k_binB<<<NBKT, 1024, 0, stream>>>(gcur, pairs, csr, startdeg, dinv);
  k_norm_bn<<<NN / 4, 256, 0, stream>>>(x, gamma, beta, mean, var, dinv, Ah, zp);
  k_aggregate<<<NN / 8, 256, 0, stream>>>(zp, Ah, startdeg, csr, dinv);
  k_gemm<<<(NN + 255) / 256, 512, 0, stream>>>(Ah, WhT, bias2, out);
}

// Round 12
// 257.002 us; speedup vs baseline: 1.2047x; 1.0606x over previous
//
#include <hip/hip_runtime.h>
#include <hip/hip_fp16.h>

// GNN fused pipeline on MI355X (gfx950).
//   CSR by dst via two-level counting sort, both levels LDS-staged so all
//   global writes are coalesced (binA block-local sort, binB bucket sort)
//   norm_bn: z = BN(l2normalize(x)) -> Ah cols 128..255 (fp16)
//            zp = dinv*z            -> dense fp16 gather array
//   aggregate: y[i] = dinv_i*(sum_j zp[j] + zp[i]) -> Ah cols 0..127
//              (quarter-wave per node: 32 row-loads in flight per wave)
//   out = leaky( Ah @ WhT^T + bias2 )  fp16 MFMA 16x16x32, B staged in LDS

#define NN 100000
#define DD 128
#define EE 1600000
#define BN_EPS 1e-5f
#define SLOPE 0.01f

#define NBKT 98          // ceil(NN / 1024)
#define BWID 1024        // nodes per bucket (dst >> 10)
#define CAPP 20480       // global slack capacity per bucket (mean 16327, sd ~128)
#define LCAP 18432       // binB LDS sort capacity (mean + 16 sd)
#define EPB  4096        // edges per binA block
#define EBLK 391         // (EE + EPB - 1) / EPB

typedef _Float16 f16x8 __attribute__((ext_vector_type(8)));
typedef float    f32x4 __attribute__((ext_vector_type(4)));

// Phase A: blocks 0..390 sort their 4096 edges by coarse bucket in LDS, then
// copy each run to its reserved global chunk with coalesced writes.
// Blocks 391..519: WhT transpose + bias (absorbed prep).
// pairs[] entry: (local_dst << 17) | src
__global__ __launch_bounds__(256) void k_binA(const int* __restrict__ src,
                                              const int* __restrict__ dst,
                                              int* __restrict__ gcur,
                                              int* __restrict__ pairs,
                                              const float* __restrict__ W,
                                              const float* __restrict__ rsW,
                                              const float* __restrict__ b,
                                              const float* __restrict__ rb,
                                              __half* __restrict__ WhT,
                                              float* __restrict__ bias2) {
  int t = threadIdx.x;
  if (blockIdx.x >= EBLK) {
    int blk = blockIdx.x - EBLK;
    if (blk == 128) {
      if (t < DD) bias2[t] = b[t] + rb[t];
    } else {
      float v = (t < 128) ? W[t * 128 + blk] : rsW[(t - 128) * 128 + blk];
      WhT[blk * 256 + t] = __float2half(v);
    }
    return;
  }
  __shared__ int hist[NBKT];
  __shared__ int cur[NBKT];
  __shared__ int gofs[NBKT];
  __shared__ int wtot;
  __shared__ int sortedp[EPB];
  __shared__ unsigned char sbk[EPB];
  if (t < NBKT) hist[t] = 0;
  __syncthreads();
  int e0 = blockIdx.x * EPB;
  int pr[16];
  int bkr[16];
  #pragma unroll
  for (int i = 0; i < 16; ++i) {
    int e = e0 + i * 256 + t;
    bkr[i] = -1;
    if (e < EE) {
      int d = dst[e], s = src[e];
      bkr[i] = d >> 10;
      pr[i] = ((d & 1023) << 17) | s;
      atomicAdd(&hist[bkr[i]], 1);
    }
  }
  __syncthreads();
  // exclusive scan of hist[0..97] across 2 waves
  {
    int v = (t < NBKT) ? hist[t] : 0;
    int incl = v;
    #pragma unroll
    for (int off = 1; off < 64; off <<= 1) {
      int n = __shfl_up(incl, off, 64);
      if ((t & 63) >= off) incl += n;
    }
    if (t == 63) wtot = incl;
    __syncthreads();
    if (t < NBKT) {
      int ex = incl - v + ((t >= 64) ? wtot : 0);
      cur[t] = ex;
      int gb = atomicAdd(&gcur[t], v);          // relative base within bucket
      gofs[t] = t * CAPP + gb - ex;
    }
  }
  __syncthreads();
  // scatter into LDS sorted order
  #pragma unroll
  for (int i = 0; i < 16; ++i) {
    if (bkr[i] >= 0) {
      int r = atomicAdd(&cur[bkr[i]], 1);
      sortedp[r] = pr[i];
      sbk[r] = (unsigned char)bkr[i];
    }
  }
  __syncthreads();
  // coalesced copy-out (consecutive i are mostly the same bucket run)
  int cnt = min(EPB, EE - e0);
  for (int i = t; i < cnt; i += 256) {
    int bq = sbk[i];
    pairs[gofs[bq] + i] = sortedp[i];
  }
}

// Phase B: one block per bucket; LDS histogram + scan -> dinv, startdeg;
// scatter into LDS sorted buffer, then coalesced csr write-out.
__global__ __launch_bounds__(1024) void k_binB(const int* __restrict__ gcur,
                                               const int* __restrict__ pairs,
                                               int* __restrict__ csr,
                                               int2* __restrict__ startdeg,
                                               float* __restrict__ dinv) {
  __shared__ int hist[BWID];
  __shared__ int excl[BWID];
  __shared__ int wsum[16];
  __shared__ int sortedp[LCAP];
  int b = blockIdx.x, t = threadIdx.x;
  hist[t] = 0;
  __syncthreads();
  int pbase = b * CAPP;
  int cnt = gcur[b];
  if (cnt > LCAP) cnt = LCAP;   // statistically impossible; safety clamp
  for (int i = t; i < cnt; i += BWID)
    atomicAdd(&hist[pairs[pbase + i] >> 17], 1);
  __syncthreads();
  int v = hist[t];
  int lane = t & 63, w = t >> 6;
  int incl = v;
  #pragma unroll
  for (int off = 1; off < 64; off <<= 1) {
    int n = __shfl_up(incl, off, 64);
    if (lane >= off) incl += n;
  }
  if (lane == 63) wsum[w] = incl;
  __syncthreads();
  if (t < 16) {
    int orig = wsum[t];
    int s = orig;
    #pragma unroll
    for (int off = 1; off < 16; off <<= 1) {
      int n = __shfl_up(s, off, 64);
      if (t >= off) s += n;
    }
    wsum[t] = s - orig;
  }
  __syncthreads();
  int myexcl = (incl - v) + wsum[w];
  excl[t] = myexcl;
  int node = b * BWID + t;
  if (node < NN) {
    dinv[node] = rsqrtf((float)(v + 1));               // +1 self-loop
    startdeg[node] = make_int2(pbase + myexcl, v);
  }
  __syncthreads();
  for (int i = t; i < cnt; i += BWID) {
    int p = pairs[pbase + i];
    int pos = atomicAdd(&excl[p >> 17], 1);
    sortedp[pos] = p & 0x1FFFF;
  }
  __syncthreads();
  for (int i = t; i < cnt; i += BWID)
    csr[pbase + i] = sortedp[i];
}

// fused row L2-normalize + BatchNorm(eval); one 64-lane wave per row.
// Writes fp16 z into Ah cols 128..255 and zp = dinv*z (dense fp16).
__global__ void k_norm_bn(const float* __restrict__ x,
                          const float* __restrict__ gamma,
                          const float* __restrict__ beta,
                          const float* __restrict__ mean,
                          const float* __restrict__ var,
                          const float* __restrict__ dinv,
                          __half* __restrict__ Ah, __half* __restrict__ zp) {
  int row = blockIdx.x * 4 + (threadIdx.x >> 6);
  int lane = threadIdx.x & 63;
  if (row >= NN) return;
  float2 v = ((const float2*)(x + (size_t)row * DD))[lane];
  float ss = v.x * v.x + v.y * v.y;
  #pragma unroll
  for (int off = 32; off > 0; off >>= 1) ss += __shfl_xor(ss, off);
  float s = 1.0f / fmaxf(sqrtf(ss), 1e-12f);
  float di = dinv[row];
  int c = lane * 2;
  float g0 = gamma[c]     * rsqrtf(var[c]     + BN_EPS);
  float g1 = gamma[c + 1] * rsqrtf(var[c + 1] + BN_EPS);
  float ox = (v.x * s - mean[c])     * g0 + beta[c];
  float oy = (v.y * s - mean[c + 1]) * g1 + beta[c + 1];
  ((__half2*)(Ah + (size_t)row * 256 + 128))[lane] = __floats2half2_rn(ox, oy);
  ((__half2*)(zp + (size_t)row * DD))[lane] = __floats2half2_rn(di * ox, di * oy);
}

// y[i] = dinv_i * ( sum_j zp[j] + zp[i] );  zp premultiplied fp16, dense.
// QUARTER-wave per node: 16 lanes x f16x8 (16B) cover a 256B row; 8-deep
// unroll per quarter => 32 row-loads in flight per wave.
__global__ void k_aggregate(const __half* __restrict__ zp,
                            __half* __restrict__ Ah,
                            const int2* __restrict__ startdeg,
                            const int* __restrict__ csr,
                            const float* __restrict__ dinv) {
  int lane = threadIdx.x & 63;
  int q   = lane >> 4;
  int l16 = lane & 15;
  int node = blockIdx.x * 16 + (threadIdx.x >> 6) * 4 + q;
  int2 sd = startdeg[node];
  int k = sd.x, end = sd.x + sd.y;
  float di = dinv[node];
  const f16x8* zr = (const f16x8*)zp;      // row stride = 16 f16x8
  float acc[8] = {0.f, 0.f, 0.f, 0.f, 0.f, 0.f, 0.f, 0.f};
  for (; k + 8 <= end; k += 8) {
    int j[8];
    #pragma unroll
    for (int u = 0; u < 8; ++u) j[u] = csr[k + u];
    f16x8 a[8];
    #pragma unroll
    for (int u = 0; u < 8; ++u) a[u] = zr[(size_t)j[u] * 16 + l16];
    #pragma unroll
    for (int u = 0; u < 8; ++u)
      #pragma unroll
      for (int vv = 0; vv < 8; ++vv) acc[vv] += (float)a[u][vv];
  }
  if (k + 4 <= end) {
    int j[4];
    #pragma unroll
    for (int u = 0; u < 4; ++u) j[u] = csr[k + u];
    f16x8 a[4];
    #pragma unroll
    for (int u = 0; u < 4; ++u) a[u] = zr[(size_t)j[u] * 16 + l16];
    #pragma unroll
    for (int u = 0; u < 4; ++u)
      #pragma unroll
      for (int vv = 0; vv < 8; ++vv) acc[vv] += (float)a[u][vv];
    k += 4;
  }
  for (; k < end; ++k) {
    int j0 = csr[k];
    f16x8 a0 = zr[(size_t)j0 * 16 + l16];
    #pragma unroll
    for (int vv = 0; vv < 8; ++vv) acc[vv] += (float)a0[vv];
  }
  f16x8 zs = zr[(size_t)node * 16 + l16];  // zp[i] self-term
  f16x8 o;
  #pragma unroll
  for (int vv = 0; vv < 8; ++vv)
    o[vv] = (_Float16)((acc[vv] + (float)zs[vv]) * di);
  ((f16x8*)Ah)[(size_t)node * 32 + l16] = o;   // Ah row = 32 f16x8; y = 0..15
}

// out = leaky( Ah(N x 256) @ WhT^T + bias2 ) via mfma_f32_16x16x32_f16.
// 256 threads = 4 waves, 128 rows/block (782 blocks: no tail cliff, 2
// blocks/CU overlap). WhT (64 KB) staged in LDS with XOR swizzle
// (byte ^= (row&7)<<4 on both write and read).
__global__ __launch_bounds__(256) void k_gemm(
    const __half* __restrict__ Ah, const __half* __restrict__ WhT,
    const float* __restrict__ bias2, float* __restrict__ out) {
  __shared__ __align__(16) char Bs[65536];
  const int tid = threadIdx.x;
  const int w  = tid >> 6;
  const int l  = tid & 63;
  const int lm = l & 15;
  const int lk = l >> 4;
  const int row0 = blockIdx.x * 128 + w * 32;

  int rA0 = row0 + lm;
  int rA1 = row0 + 16 + lm;
  if (rA0 >= NN) rA0 = NN - 1;   // clamp; stores are guarded
  if (rA1 >= NN) rA1 = NN - 1;

  const __half* a0p = Ah + (size_t)rA0 * 256 + lk * 8;
  const __half* a1p = Ah + (size_t)rA1 * 256 + lk * 8;
  f16x8 a0[8], a1[8];
  #pragma unroll
  for (int ks = 0; ks < 8; ++ks) {
    a0[ks] = *(const f16x8*)(a0p + ks * 32);
    a1[ks] = *(const f16x8*)(a1p + ks * 32);
  }

  #pragma unroll
  for (int i = 0; i < 16; ++i) {
    int idx = tid + i * 256;              // float4 index over 64 KB
    int byte = idx * 16;
    int swz = byte ^ (((byte >> 9) & 7) << 4);
    *(float4*)(Bs + swz) = ((const float4*)WhT)[idx];
  }
  __syncthreads();

  f32x4 acc0[8], acc1[8];
  #pragma unroll
  for (int c = 0; c < 8; ++c) {
    acc0[c] = (f32x4)(0.f);
    acc1[c] = (f32x4)(0.f);
  }

  #pragma unroll
  for (int ks = 0; ks < 8; ++ks) {
    #pragma unroll
    for (int c = 0; c < 8; ++c) {
      int byte = (c * 16 + lm) * 512 + lk * 16 + ks * 64;
      f16x8 b = *(const f16x8*)(Bs + (byte ^ ((lm & 7) << 4)));
      acc0[c] = __builtin_amdgcn_mfma_f32_16x16x32_f16(a0[ks], b, acc0[c], 0, 0, 0);
      acc1[c] = __builtin_amdgcn_mfma_f32_16x16x32_f16(a1[ks], b, acc1[c], 0, 0, 0);
    }
  }

  int orow0 = row0 + lk * 4;
  int orow1 = row0 + 16 + lk * 4;
  #pragma unroll
  for (int c = 0; c < 8; ++c) {
    int col = c * 16 + lm;
    float bs = bias2[col];
    #pragma unroll
    for (int r = 0; r < 4; ++r) {
      int g0 = orow0 + r;
      if (g0 < NN) {
        float v = acc0[c][r] + bs;
        out[(size_t)g0 * 128 + col] = (v >= 0.f) ? v : SLOPE * v;
      }
      int g1 = orow1 + r;
      if (g1 < NN) {
        float v = acc1[c][r] + bs;
        out[(size_t)g1 * 128 + col] = (v >= 0.f) ? v : SLOPE * v;
      }
    }
  }
}

extern "C" void kernel_launch(void* const* d_in, const int* in_sizes, int n_in,
                              void* d_out, int out_size, void* d_ws, size_t ws_size,
                              hipStream_t stream) {
  const float* x     = (const float*)d_in[0];
  const int*   ei    = (const int*)d_in[1];
  const float* W     = (const float*)d_in[2];
  const float* b     = (const float*)d_in[3];
  const float* gamma = (const float*)d_in[4];
  const float* beta  = (const float*)d_in[5];
  const float* mean  = (const float*)d_in[6];
  const float* var   = (const float*)d_in[7];
  const float* rsW   = (const float*)d_in[8];
  const float* rsb   = (const float*)d_in[9];
  float* out = (float*)d_out;
  const int* src = ei;         // edge_index[0]
  const int* dst = ei + EE;    // edge_index[1]

  // workspace carve-up (~94 MB)
  __half* Ah       = (__half*)d_ws;                     // NN*256 f16
  __half* zp       = Ah + (size_t)NN * 256;             // NN*128 f16
  int2*   startdeg = (int2*)(zp + (size_t)NN * DD);     // NN int2
  float*  dinv     = (float*)(startdeg + NN);           // NN f32
  int*    gcur     = (int*)(dinv + NN);                 // NBKT (pad 128)
  int*    pairs    = gcur + 128;                        // NBKT*CAPP
  int*    csr      = pairs + NBKT * CAPP;               // NBKT*CAPP
  __half* WhT      = (__half*)(csr + NBKT * CAPP);      // 128*256 f16
  float*  bias2    = (float*)(WhT + 128 * 256);         // DD f32

  hipMemsetAsync(gcur, 0, 128 * sizeof(int), stream);
  k_binA<<<EBLK + 129, 256, 0, stream>>>(src, dst, gcur, pairs,
                                         W, rsW, b, rsb, WhT, bias2);
  k_binB<<<NBKT, 1024, 0, stream>>>(gcur, pairs, csr, startdeg, dinv);
  k_norm_bn<<<NN / 4, 256, 0, stream>>>(x, gamma, beta, mean, var, dinv, Ah, zp);
  k_aggregate<<<NN / 16, 256, 0, stream>>>(zp, Ah, startdeg, csr, dinv);
  k_gemm<<<(NN + 127) / 128, 256, 0, stream>>>(Ah, WhT, bias2, out);
}